// Round 10
// baseline (497.879 us; speedup 1.0000x reference)
//
#include <hip/hip_runtime.h>
#include <math.h>

// ---------------------------------------------------------------------------
// SABlock: x[B,C,H,W] -> depthwise3x3+res -> [B,N,C]: LN1 -> QKV -> flash-MHA
//          -> proj +res -> LN2 -> FC1 -> GELU -> FC2 -> +res -> [B,C,H,W]
// R16: conv_pe_t + ln1 FUSED into conv_ln (grid 32h x 8b = 256 blocks; full
// 768-ch x 32-tok tile in LDS [32][780]; in-block LN reduce; one coalesced
// write pass emits t0 AND lnout). Kills one launch + the 25MB t0 re-read.
// qkv/proj (gemm_pipe tribuf), fc1 (R9 4-phase), fc2 (R10 tribuf), flash
// (head-per-XCD) byte-identical -- all at their measured-best forms.
// ---------------------------------------------------------------------------

typedef __bf16 bf16;
typedef __attribute__((ext_vector_type(8))) __bf16 bf16x8;
typedef __attribute__((ext_vector_type(4))) __bf16 bf16x4;
typedef __attribute__((ext_vector_type(4))) float f32x4;

#define B_   8
#define C_   768
#define N_   1024
#define NH_  12
#define HD_  64
#define HID_ 3072
#define NTOK   (B_ * N_)     // 8192
#define NHEADS (B_ * NH_)    // 96
#define FA_C   0.1803368801111601f  // 0.125 * log2(e)

__device__ __forceinline__ void gload_lds16(const void* g, void* l) {
  __builtin_amdgcn_global_load_lds(
      (__attribute__((address_space(1))) void*)(void*)g,
      (__attribute__((address_space(3))) void*)l, 16, 0, 0);
}

__device__ __forceinline__ float gelu1(float x) {
  // tanh-form GELU via exp2; |err| well under bf16 noise (verified R4/R5)
  float u = 0.7978845608028654f * x * (1.0f + 0.044715f * x * x);
  float e = __builtin_amdgcn_exp2f(u * 2.885390081777927f);  // exp(2u)
  float th = 1.0f - 2.0f * __builtin_amdgcn_rcpf(e + 1.0f);
  return 0.5f * x * (1.0f + th);
}

// counted-vmcnt phase boundary: vmcnt+lgkm BEFORE the raw barrier.
#define PIPE_SYNC(N)                                              \
  do {                                                            \
    asm volatile("s_waitcnt vmcnt(" #N ") lgkmcnt(0)" ::: "memory"); \
    __builtin_amdgcn_sched_barrier(0);                            \
    __builtin_amdgcn_s_barrier();                                 \
    __builtin_amdgcn_sched_barrier(0);                            \
    asm volatile("" ::: "memory");                                \
  } while (0)

// ---------------------------------------------------------------------------
// conv_ln: depthwise 3x3 conv + bias + residual + LayerNorm, fused.
// Grid 256 = (32 h-rows) x (8 batches); 256 thr (w = tid&31, cg = tid>>5).
// Each block owns 32 tokens (one h-row) x all 768 channels:
//   pass A (12 chunks of 64 ch): thread computes 8 ch x 1 w conv outputs
//     (9-tap + residual + bias, global loads with L1 reuse), stores to LDS
//     vals[w][ch] (row stride 780: 16B-aligned rows; write aliasing 4-way
//     only), accumulates per-thread sum/sumsq over its 96 channels.
//   pass B: 8-way cg reduction -> mu[w], rstd[w].
//   pass C: coalesced write pass (wave = 2 toks x 32 ch-lanes): emits
//     t0[tok][ch] (f32) and lnout[tok][ch] = LN (bf16) from LDS.
// Saves the ln1 launch + 25MB t0 round-trip vs conv_pe_t + ln_bf16.
// ---------------------------------------------------------------------------
__global__ __launch_bounds__(256) void conv_ln(
    const float* __restrict__ x, const float* __restrict__ cw,
    const float* __restrict__ cb, const float* __restrict__ g,
    const float* __restrict__ be, float* __restrict__ t0,
    bf16* __restrict__ lnout) {
  __shared__ float vals[32][780];     // 99,840 B; rows 16B-aligned
  __shared__ float sred[8][32], qred[8][32];
  __shared__ float mufin[32], rsfin[32];
  const int tid = threadIdx.x;
  const int w = tid & 31, cg = tid >> 5;
  const int h = blockIdx.x & 31, b = blockIdx.x >> 5;

  float sacc = 0.f, qacc = 0.f;
  for (int chunk = 0; chunk < 12; ++chunk) {
#pragma unroll
    for (int q = 0; q < 8; ++q) {
      const int ch = chunk * 64 + cg * 8 + q;
      const float* xp = x + ((size_t)(b * C_ + ch)) * 1024;
      const float* wp = cw + ch * 9;
      float s = cb[ch] + xp[h * 32 + w];
#pragma unroll
      for (int ky = 0; ky < 3; ++ky) {
        int hy = h + ky - 1;
        if ((unsigned)hy < 32u) {
#pragma unroll
          for (int kx = 0; kx < 3; ++kx) {
            int wx = w + kx - 1;
            if ((unsigned)wx < 32u) s += xp[hy * 32 + wx] * wp[ky * 3 + kx];
          }
        }
      }
      vals[w][ch] = s;
      sacc += s;
      qacc += s * s;
    }
  }
  sred[cg][w] = sacc;
  qred[cg][w] = qacc;
  __syncthreads();
  if (tid < 32) {
    float s = 0.f, qq = 0.f;
#pragma unroll
    for (int c = 0; c < 8; ++c) { s += sred[c][tid]; qq += qred[c][tid]; }
    float mu = s * (1.f / C_);
    float var = qq * (1.f / C_) - mu * mu;
    mufin[tid] = mu;
    rsfin[tid] = rsqrtf(var + 1e-5f);
  }
  __syncthreads();
  // write pass: wave covers 2 toks x 32 ch-lanes -> coalesced rows
#pragma unroll
  for (int rep = 0; rep < 4; ++rep) {
    const int tok = rep * 8 + (tid >> 5);
    const float mu = mufin[tok], rs = rsfin[tok];
    const size_t row = (size_t)(b * N_ + h * 32 + tok);
    float* tp = t0 + row * C_;
    bf16* lp = lnout + row * C_;
#pragma unroll
    for (int seg = 0; seg < 6; ++seg) {
      const int ch = seg * 128 + (tid & 31) * 4;
      const f32x4 v = *(const f32x4*)&vals[tok][ch];
      *(f32x4*)(tp + ch) = v;
      const f32x4 gv = *(const f32x4*)(g + ch);
      const f32x4 bv = *(const f32x4*)(be + ch);
      bf16x4 pk = {(bf16)((v[0] - mu) * rs * gv[0] + bv[0]),
                   (bf16)((v[1] - mu) * rs * gv[1] + bv[1]),
                   (bf16)((v[2] - mu) * rs * gv[2] + bv[2]),
                   (bf16)((v[3] - mu) * rs * gv[3] + bv[3])};
      *(bf16x4*)(lp + ch) = pk;
    }
  }
}

// ---------------------------------------------------------------------------
// gemm_pipe<EPI>: 128x192-tile pipelined B^T GEMM (fc2-tribuf structure).
// 512 thr = 8 waves (2 Wm x 4 Wc); wave tile 64x48 (4 m-frags x 3 n-frags).
// LDS: 3 buffers x (A 16KB + B 24KB) = 120 KB; prefetch distance 2 K-tiles;
// one PIPE_SYNC(5) per K-tile (never drains mid-loop). Last tile peeled.
// Swizzle: chunk slot = c ^ (row&7) (0 bank conflicts). REMAP: bid&7 = XCD
// owns 8 m-tiles x all ntiles n-tiles.
// EPI 0: QKV scatter -- n0<768 -> Q, <1536 -> K (per-head bf16x4 stores,
//        [head][tok][d]); else V via 192x128 swizzled LDS bounce ->
//        coalesced V^T bf16x8 rows [head][d][tok].
// EPI 1: proj: resid float4 RMW += acc + bias.
// ---------------------------------------------------------------------------
template <int EPI>
__global__ __launch_bounds__(512) void gemm_pipe(
    const bf16* __restrict__ A, const bf16* __restrict__ Bw, int K, int lda,
    int ldb, int ntiles, bf16* __restrict__ o0, bf16* __restrict__ o1,
    bf16* __restrict__ o2, float* __restrict__ resid,
    const float* __restrict__ bias) {
  __shared__ __align__(16) char smem[122880];
  const int tid = threadIdx.x;
  const int wave = tid >> 6, lane = tid & 63;
  const int wr = wave & 1, wc = wave >> 1;
  const int lr = lane & 15, kq = lane >> 4;

  const int bid = blockIdx.x;
  const int g = bid & 7, s = bid >> 3;
  const int ms = s / ntiles;
  const int m0 = (g * 8 + ms) * 128;
  const int n0 = (s - ms * ntiles) * 192;

  f32x4 acc[4][3];
#pragma unroll
  for (int i = 0; i < 4; ++i)
#pragma unroll
    for (int j = 0; j < 3; ++j) acc[i][j] = (f32x4){0.f, 0.f, 0.f, 0.f};

  const bf16* pa[2];
  const bf16* pb[3];
  int da[2], db[3];
#pragma unroll
  for (int c = 0; c < 2; ++c) {
    const int sidx = c * 512 + tid;
    const int r = sidx >> 3, seg = (sidx & 7) ^ (r & 7);
    pa[c] = A + (size_t)(m0 + r) * lda + seg * 8;
    da[c] = sidx * 16;
  }
#pragma unroll
  for (int c = 0; c < 3; ++c) {
    const int sidx = c * 512 + tid;
    const int r = sidx >> 3, seg = (sidx & 7) ^ (r & 7);
    pb[c] = Bw + (size_t)(n0 + r) * ldb + seg * 8;
    db[c] = 16384 + sidx * 16;
  }

  const int NT = K >> 6;

  // prologue: stage tiles 0 (buf0) and 1 (buf1); 10 loads in flight
#pragma unroll
  for (int tt = 0; tt < 2; ++tt) {
    char* wb = smem + tt * 40960;
    gload_lds16(pb[0], wb + db[0]);
    gload_lds16(pb[1], wb + db[1]);
    gload_lds16(pb[2], wb + db[2]);
    gload_lds16(pa[0], wb + da[0]);
    gload_lds16(pa[1], wb + da[1]);
    pb[0] += 64; pb[1] += 64; pb[2] += 64; pa[0] += 64; pa[1] += 64;
  }

  int cur = 0;
  for (int t = 0; t < NT - 1; ++t) {
    const char* rb = smem + cur * 40960;
    PIPE_SYNC(5);
    if (t < NT - 2) {
      int wi = cur + 2; if (wi >= 3) wi -= 3;
      char* wb = smem + wi * 40960;
      gload_lds16(pb[0], wb + db[0]); pb[0] += 64;
      gload_lds16(pb[1], wb + db[1]); pb[1] += 64;
      gload_lds16(pb[2], wb + db[2]); pb[2] += 64;
      gload_lds16(pa[0], wb + da[0]); pa[0] += 64;
      gload_lds16(pa[1], wb + da[1]); pa[1] += 64;
    }
    bf16x8 af[4], bf[3];
    // ---- k-half 0
#pragma unroll
    for (int i = 0; i < 4; ++i) {
      const int r = wr * 64 + i * 16 + lr;
      af[i] = *(const bf16x8*)(rb + (r * 8 + (kq ^ (r & 7))) * 16);
    }
#pragma unroll
    for (int j = 0; j < 3; ++j) {
      const int r = wc * 48 + j * 16 + lr;
      bf[j] = *(const bf16x8*)(rb + 16384 + (r * 8 + (kq ^ (r & 7))) * 16);
    }
    __builtin_amdgcn_s_setprio(1);
#pragma unroll
    for (int i = 0; i < 4; ++i)
#pragma unroll
      for (int j = 0; j < 3; ++j)
        acc[i][j] = __builtin_amdgcn_mfma_f32_16x16x32_bf16(bf[j], af[i],
                                                            acc[i][j], 0, 0, 0);
    __builtin_amdgcn_s_setprio(0);
    // ---- k-half 1
#pragma unroll
    for (int i = 0; i < 4; ++i) {
      const int r = wr * 64 + i * 16 + lr;
      af[i] = *(const bf16x8*)(rb + (r * 8 + ((4 + kq) ^ (r & 7))) * 16);
    }
#pragma unroll
    for (int j = 0; j < 3; ++j) {
      const int r = wc * 48 + j * 16 + lr;
      bf[j] = *(const bf16x8*)(rb + 16384 + (r * 8 + ((4 + kq) ^ (r & 7))) * 16);
    }
    __builtin_amdgcn_s_setprio(1);
#pragma unroll
    for (int i = 0; i < 4; ++i)
#pragma unroll
      for (int j = 0; j < 3; ++j)
        acc[i][j] = __builtin_amdgcn_mfma_f32_16x16x32_bf16(bf[j], af[i],
                                                            acc[i][j], 0, 0, 0);
    __builtin_amdgcn_s_setprio(0);
    if (++cur == 3) cur = 0;
  }

  {  // ---- last K-tile, peeled: full drain, no staging
    const char* rb = smem + cur * 40960;
    bf16x8 af[4], bf[3];
    PIPE_SYNC(0);
#pragma unroll
    for (int kh = 0; kh < 2; ++kh) {
      const int c0 = kh * 4 + kq;
#pragma unroll
      for (int i = 0; i < 4; ++i) {
        const int r = wr * 64 + i * 16 + lr;
        af[i] = *(const bf16x8*)(rb + (r * 8 + (c0 ^ (r & 7))) * 16);
      }
#pragma unroll
      for (int j = 0; j < 3; ++j) {
        const int r = wc * 48 + j * 16 + lr;
        bf[j] = *(const bf16x8*)(rb + 16384 + (r * 8 + (c0 ^ (r & 7))) * 16);
      }
      __builtin_amdgcn_s_setprio(1);
#pragma unroll
      for (int i = 0; i < 4; ++i)
#pragma unroll
        for (int j = 0; j < 3; ++j)
          acc[i][j] = __builtin_amdgcn_mfma_f32_16x16x32_bf16(bf[j], af[i],
                                                              acc[i][j], 0, 0, 0);
      __builtin_amdgcn_s_setprio(0);
    }
  }

  if constexpr (EPI == 0) {
    const int b = m0 >> 10, tok0 = m0 & (N_ - 1);
    if (n0 < 2 * C_) {
      // Q or K: vector bf16x4 stores, [head][tok][d]
      const int sdx = n0 >= C_ ? 1 : 0;
      bf16* dst = sdx ? o1 : o0;
      const int nb = n0 - sdx * C_;
#pragma unroll
      for (int j = 0; j < 3; ++j) {
        const int rem = nb + wc * 48 + j * 16 + kq * 4;
        const int h = rem >> 6, d = rem & 63;
        bf16* hp = dst + (size_t)(b * NH_ + h) * (N_ * HD_) + d;
#pragma unroll
        for (int i = 0; i < 4; ++i) {
          const int tok = tok0 + wr * 64 + i * 16 + lr;
          const f32x4 v = acc[i][j];
          bf16x4 pk = {(bf16)v[0], (bf16)v[1], (bf16)v[2], (bf16)v[3]};
          *(bf16x4*)(hp + (size_t)tok * HD_) = pk;
        }
      }
    } else {
      // V: swizzled LDS bounce (192 rows x 128 toks) -> V^T bf16x8 rows
      bf16* tile = (bf16*)smem;
#pragma unroll
      for (int i = 0; i < 4; ++i) {
        const int ml = wr * 64 + i * 16 + lr;
        const int mc = ml >> 3, mo = ml & 7;
#pragma unroll
        for (int j = 0; j < 3; ++j) {
          const f32x4 v = acc[i][j];
#pragma unroll
          for (int r = 0; r < 4; ++r) {
            const int nl = wc * 48 + j * 16 + kq * 4 + r;
            *(bf16*)((char*)tile + nl * 256 + ((mc ^ (nl & 15)) * 16) + mo * 2) =
                (bf16)v[r];
          }
        }
      }
      __syncthreads();
      const int vbase = n0 - 2 * C_;
#pragma unroll
      for (int c = 0; c < 6; ++c) {
        const int idx = c * 512 + tid;
        const int row = idx >> 4, ch = idx & 15;
        bf16x8 val = *(const bf16x8*)((char*)tile + row * 256 +
                                      ((ch ^ (row & 15)) * 16));
        const int vb = vbase + row;
        bf16* dstp = o2 + ((size_t)(b * NH_ + (vb >> 6)) * HD_ + (vb & 63)) * N_ +
                     tok0 + ch * 8;
        *(bf16x8*)dstp = val;
      }
    }
  } else {
    // proj: resid float4 RMW += acc + bias
#pragma unroll
    for (int j = 0; j < 3; ++j) {
      const int n = n0 + wc * 48 + j * 16 + kq * 4;
      const f32x4 bv = *(const f32x4*)(bias + n);
#pragma unroll
      for (int i = 0; i < 4; ++i) {
        const int m = m0 + wr * 64 + i * 16 + lr;
        float* rp = resid + (size_t)m * C_ + n;
        f32x4 old = *(const f32x4*)rp;
        const f32x4 v = acc[i][j];
        f32x4 nw = {old[0] + v[0] + bv[0], old[1] + v[1] + bv[1],
                    old[2] + v[2] + bv[2], old[3] + v[3] + bv[3]};
        *(f32x4*)rp = nw;
      }
    }
  }
}

// ---------------------------------------------------------------------------
// fc1: 256x192-tile pipelined B^T GEMM + GELU epilogue. (R9-best, 56.1us.)
// Grid 512 = 32 m-tiles x 16 n-tiles = EXACTLY 2 rounds at 1 block/CU.
// ---------------------------------------------------------------------------
__global__ __launch_bounds__(512) void gemm_fc1(
    const bf16* __restrict__ A, const bf16* __restrict__ Bw,
    const float* __restrict__ bias, bf16* __restrict__ outp,
    int K, int lda, int ldb, int ntiles, int mtpx, int ldo) {
  __shared__ __align__(16) char smem[114688];
  const int tid = threadIdx.x;
  const int wave = tid >> 6, lane = tid & 63;
  const int wr = wave & 1, wc = wave >> 1;
  const int lr = lane & 15, kq = lane >> 4;

  const int bid = blockIdx.x;
  const int g = bid & 7, s = bid >> 3;
  const int ms = s / ntiles;
  const int m0 = (g * mtpx + ms) * 256;
  const int n0 = (s - ms * ntiles) * 192;

  f32x4 acc[8][3];
#pragma unroll
  for (int i = 0; i < 8; ++i)
#pragma unroll
    for (int j = 0; j < 3; ++j) acc[i][j] = (f32x4){0.f, 0.f, 0.f, 0.f};

  const bf16* pa[4];
  const bf16* pb[3];
  int da[4], db[3];
#pragma unroll
  for (int c = 0; c < 4; ++c) {
    const int sidx = c * 512 + tid;
    const int r = sidx >> 3, seg = (sidx & 7) ^ (r & 7);
    pa[c] = A + (size_t)(m0 + r) * lda + seg * 8;
    da[c] = sidx * 16;
  }
#pragma unroll
  for (int c = 0; c < 3; ++c) {
    const int sidx = c * 512 + tid;
    const int r = sidx >> 3, seg = (sidx & 7) ^ (r & 7);
    pb[c] = Bw + (size_t)(n0 + r) * ldb + seg * 8;
    db[c] = 32768 + sidx * 16;
  }

  const int NT = K >> 6;

  gload_lds16(pb[0], smem + db[0]);
  gload_lds16(pb[1], smem + db[1]);
  gload_lds16(pb[2], smem + db[2]);
  gload_lds16(pa[0], smem + da[0]);
  gload_lds16(pa[1], smem + da[1]);
  gload_lds16(pa[2], smem + da[2]);
  gload_lds16(pa[3], smem + da[3]);
#pragma unroll
  for (int c = 0; c < 4; ++c) pa[c] += 64;
#pragma unroll
  for (int c = 0; c < 3; ++c) pb[c] += 64;

  for (int t = 0; t < NT - 1; ++t) {
    const char* rb = smem + (t & 1) * 57344;
    char* wb = smem + ((t & 1) ^ 1) * 57344;
    bf16x8 af[4], bf0[3], bf1[3];

    // ---- ph0: k0 x m-rows[0..63 of half] + all B k0; stage B0,B1
    PIPE_SYNC(1);
#pragma unroll
    for (int i = 0; i < 4; ++i) {
      const int r = wr * 128 + i * 16 + lr;
      af[i] = *(const bf16x8*)(rb + (r * 8 + (kq ^ (r & 7))) * 16);
    }
#pragma unroll
    for (int j = 0; j < 3; ++j) {
      const int r = wc * 48 + j * 16 + lr;
      bf0[j] = *(const bf16x8*)(rb + 32768 + (r * 8 + (kq ^ (r & 7))) * 16);
    }
    gload_lds16(pb[0], wb + db[0]); pb[0] += 64;
    gload_lds16(pb[1], wb + db[1]); pb[1] += 64;
    __builtin_amdgcn_s_setprio(1);
#pragma unroll
    for (int i = 0; i < 4; ++i)
#pragma unroll
      for (int j = 0; j < 3; ++j)
        acc[i][j] = __builtin_amdgcn_mfma_f32_16x16x32_bf16(bf0[j], af[i],
                                                            acc[i][j], 0, 0, 0);
    __builtin_amdgcn_s_setprio(0);

    // ---- ph1: k0 x m-rows[64..127 of half]; stage B2,A0
    PIPE_SYNC(2);
#pragma unroll
    for (int i = 0; i < 4; ++i) {
      const int r = wr * 128 + 64 + i * 16 + lr;
      af[i] = *(const bf16x8*)(rb + (r * 8 + (kq ^ (r & 7))) * 16);
    }
    gload_lds16(pb[2], wb + db[2]); pb[2] += 64;
    gload_lds16(pa[0], wb + da[0]); pa[0] += 64;
    __builtin_amdgcn_s_setprio(1);
#pragma unroll
    for (int i = 0; i < 4; ++i)
#pragma unroll
      for (int j = 0; j < 3; ++j)
        acc[4 + i][j] = __builtin_amdgcn_mfma_f32_16x16x32_bf16(
            bf0[j], af[i], acc[4 + i][j], 0, 0, 0);
    __builtin_amdgcn_s_setprio(0);

    // ---- ph2: k1 x m-rows[0..63 of half] + all B k1; stage A1,A2
    PIPE_SYNC(4);
#pragma unroll
    for (int i = 0; i < 4; ++i) {
      const int r = wr * 128 + i * 16 + lr;
      af[i] = *(const bf16x8*)(rb + (r * 8 + ((4 + kq) ^ (r & 7))) * 16);
    }
#pragma unroll
    for (int j = 0; j < 3; ++j) {
      const int r = wc * 48 + j * 16 + lr;
      bf1[j] = *(const bf16x8*)(rb + 32768 + (r * 8 + ((4 + kq) ^ (r & 7))) * 16);
    }
    gload_lds16(pa[1], wb + da[1]); pa[1] += 64;
    gload_lds16(pa[2], wb + da[2]); pa[2] += 64;
    __builtin_amdgcn_s_setprio(1);
#pragma unroll
    for (int i = 0; i < 4; ++i)
#pragma unroll
      for (int j = 0; j < 3; ++j)
        acc[i][j] = __builtin_amdgcn_mfma_f32_16x16x32_bf16(bf1[j], af[i],
                                                            acc[i][j], 0, 0, 0);
    __builtin_amdgcn_s_setprio(0);

    // ---- ph3: k1 x m-rows[64..127 of half]; stage A3
    PIPE_SYNC(6);
#pragma unroll
    for (int i = 0; i < 4; ++i) {
      const int r = wr * 128 + 64 + i * 16 + lr;
      af[i] = *(const bf16x8*)(rb + (r * 8 + ((4 + kq) ^ (r & 7))) * 16);
    }
    gload_lds16(pa[3], wb + da[3]); pa[3] += 64;
    __builtin_amdgcn_s_setprio(1);
#pragma unroll
    for (int i = 0; i < 4; ++i)
#pragma unroll
      for (int j = 0; j < 3; ++j)
        acc[4 + i][j] = __builtin_amdgcn_mfma_f32_16x16x32_bf16(
            bf1[j], af[i], acc[4 + i][j], 0, 0, 0);
    __builtin_amdgcn_s_setprio(0);
  }

  {  // ---- last K-tile, peeled: full drain, no barriers, no staging
    const char* rb = smem + ((NT - 1) & 1) * 57344;
    bf16x8 af[4], bf0[3], bf1[3];
    PIPE_SYNC(0);
#pragma unroll
    for (int j = 0; j < 3; ++j) {
      const int r = wc * 48 + j * 16 + lr;
      bf0[j] = *(const bf16x8*)(rb + 32768 + (r * 8 + (kq ^ (r & 7))) * 16);
      bf1[j] = *(const bf16x8*)(rb + 32768 + (r * 8 + ((4 + kq) ^ (r & 7))) * 16);
    }
    __builtin_amdgcn_s_setprio(1);
#pragma unroll
    for (int half = 0; half < 2; ++half) {
#pragma unroll
      for (int i = 0; i < 4; ++i) {
        const int r = wr * 128 + half * 64 + i * 16 + lr;
        af[i] = *(const bf16x8*)(rb + (r * 8 + (kq ^ (r & 7))) * 16);
      }
#pragma unroll
      for (int i = 0; i < 4; ++i)
#pragma unroll
        for (int j = 0; j < 3; ++j)
          acc[half * 4 + i][j] = __builtin_amdgcn_mfma_f32_16x16x32_bf16(
              bf0[j], af[i], acc[half * 4 + i][j], 0, 0, 0);
#pragma unroll
      for (int i = 0; i < 4; ++i) {
        const int r = wr * 128 + half * 64 + i * 16 + lr;
        af[i] = *(const bf16x8*)(rb + (r * 8 + ((4 + kq) ^ (r & 7))) * 16);
      }
#pragma unroll
      for (int i = 0; i < 4; ++i)
#pragma unroll
        for (int j = 0; j < 3; ++j)
          acc[half * 4 + i][j] = __builtin_amdgcn_mfma_f32_16x16x32_bf16(
              bf1[j], af[i], acc[half * 4 + i][j], 0, 0, 0);
    }
    __builtin_amdgcn_s_setprio(0);
  }

  // epilogue: GELU(acc + bias) -> bf16
#pragma unroll
  for (int j = 0; j < 3; ++j) {
    const int n = n0 + wc * 48 + j * 16 + kq * 4;
    const f32x4 bv = *(const f32x4*)(bias + n);
#pragma unroll
    for (int i = 0; i < 8; ++i) {
      const int m = m0 + wr * 128 + i * 16 + lr;
      const f32x4 v = acc[i][j];
      bf16x4 pk = {(bf16)gelu1(v[0] + bv[0]), (bf16)gelu1(v[1] + bv[1]),
                   (bf16)gelu1(v[2] + bv[2]), (bf16)gelu1(v[3] + bv[3])};
      *(bf16x4*)(outp + (size_t)m * ldo + n) = pk;
    }
  }
}

// ---------------------------------------------------------------------------
// fc2: 128x192-tile pipelined B^T GEMM, K=3072 (48 tiles), NCHW epilogue.
// (R10 best-known form: tribuf, distance-2 prefetch, ONE PIPE_SYNC(5) per
// K-tile.) Grid 256 = 64m x 4n = exactly ONE round.
// ---------------------------------------------------------------------------
__global__ __launch_bounds__(512) void gemm_fc2(
    const bf16* __restrict__ A, const bf16* __restrict__ Bw,
    const float* __restrict__ bias, const float* __restrict__ resid,
    float* __restrict__ outp, int K, int lda, int ldb) {
  __shared__ __align__(16) char smem[122880];
  const int tid = threadIdx.x;
  const int wave = tid >> 6, lane = tid & 63;
  const int wr = wave & 1, wc = wave >> 1;
  const int lr = lane & 15, kq = lane >> 4;

  const int bid = blockIdx.x;
  const int g = bid & 7, s = bid >> 3;
  const int ms = s >> 2;                 // 0..7
  const int m0 = (g * 8 + ms) * 128;
  const int n0 = (s & 3) * 192;

  f32x4 acc[4][3];
#pragma unroll
  for (int i = 0; i < 4; ++i)
#pragma unroll
    for (int j = 0; j < 3; ++j) acc[i][j] = (f32x4){0.f, 0.f, 0.f, 0.f};

  const bf16* pa[2];
  const bf16* pb[3];
  int da[2], db[3];
#pragma unroll
  for (int c = 0; c < 2; ++c) {
    const int sidx = c * 512 + tid;
    const int r = sidx >> 3, seg = (sidx & 7) ^ (r & 7);
    pa[c] = A + (size_t)(m0 + r) * lda + seg * 8;
    da[c] = sidx * 16;
  }
#pragma unroll
  for (int c = 0; c < 3; ++c) {
    const int sidx = c * 512 + tid;
    const int r = sidx >> 3, seg = (sidx & 7) ^ (r & 7);
    pb[c] = Bw + (size_t)(n0 + r) * ldb + seg * 8;
    db[c] = 16384 + sidx * 16;
  }

  const int NT = K >> 6;  // 48

#pragma unroll
  for (int tt = 0; tt < 2; ++tt) {
    char* wb = smem + tt * 40960;
    gload_lds16(pb[0], wb + db[0]);
    gload_lds16(pb[1], wb + db[1]);
    gload_lds16(pb[2], wb + db[2]);
    gload_lds16(pa[0], wb + da[0]);
    gload_lds16(pa[1], wb + da[1]);
    pb[0] += 64; pb[1] += 64; pb[2] += 64; pa[0] += 64; pa[1] += 64;
  }

  int cur = 0;
  for (int t = 0; t < NT - 1; ++t) {
    const char* rb = smem + cur * 40960;
    PIPE_SYNC(5);
    if (t < NT - 2) {
      int wi = cur + 2; if (wi >= 3) wi -= 3;
      char* wb = smem + wi * 40960;
      gload_lds16(pb[0], wb + db[0]); pb[0] += 64;
      gload_lds16(pb[1], wb + db[1]); pb[1] += 64;
      gload_lds16(pb[2], wb + db[2]); pb[2] += 64;
      gload_lds16(pa[0], wb + da[0]); pa[0] += 64;
      gload_lds16(pa[1], wb + da[1]); pa[1] += 64;
    }
    bf16x8 af[4], bf[3];
    // ---- k-half 0
#pragma unroll
    for (int i = 0; i < 4; ++i) {
      const int r = wr * 64 + i * 16 + lr;
      af[i] = *(const bf16x8*)(rb + (r * 8 + (kq ^ (r & 7))) * 16);
    }
#pragma unroll
    for (int j = 0; j < 3; ++j) {
      const int r = wc * 48 + j * 16 + lr;
      bf[j] = *(const bf16x8*)(rb + 16384 + (r * 8 + (kq ^ (r & 7))) * 16);
    }
    __builtin_amdgcn_s_setprio(1);
#pragma unroll
    for (int i = 0; i < 4; ++i)
#pragma unroll
      for (int j = 0; j < 3; ++j)
        acc[i][j] = __builtin_amdgcn_mfma_f32_16x16x32_bf16(bf[j], af[i],
                                                            acc[i][j], 0, 0, 0);
    __builtin_amdgcn_s_setprio(0);
    // ---- k-half 1
#pragma unroll
    for (int i = 0; i < 4; ++i) {
      const int r = wr * 64 + i * 16 + lr;
      af[i] = *(const bf16x8*)(rb + (r * 8 + ((4 + kq) ^ (r & 7))) * 16);
    }
#pragma unroll
    for (int j = 0; j < 3; ++j) {
      const int r = wc * 48 + j * 16 + lr;
      bf[j] = *(const bf16x8*)(rb + 16384 + (r * 8 + ((4 + kq) ^ (r & 7))) * 16);
    }
    __builtin_amdgcn_s_setprio(1);
#pragma unroll
    for (int i = 0; i < 4; ++i)
#pragma unroll
      for (int j = 0; j < 3; ++j)
        acc[i][j] = __builtin_amdgcn_mfma_f32_16x16x32_bf16(bf[j], af[i],
                                                            acc[i][j], 0, 0, 0);
    __builtin_amdgcn_s_setprio(0);
    if (++cur == 3) cur = 0;
  }

  {  // ---- last K-tile, peeled: full drain, no staging
    const char* rb = smem + cur * 40960;
    bf16x8 af[4], bf[3];
    PIPE_SYNC(0);
#pragma unroll
    for (int kh = 0; kh < 2; ++kh) {
      const int c0 = kh * 4 + kq;
#pragma unroll
      for (int i = 0; i < 4; ++i) {
        const int r = wr * 64 + i * 16 + lr;
        af[i] = *(const bf16x8*)(rb + (r * 8 + (c0 ^ (r & 7))) * 16);
      }
#pragma unroll
      for (int j = 0; j < 3; ++j) {
        const int r = wc * 48 + j * 16 + lr;
        bf[j] = *(const bf16x8*)(rb + 16384 + (r * 8 + (c0 ^ (r & 7))) * 16);
      }
      __builtin_amdgcn_s_setprio(1);
#pragma unroll
      for (int i = 0; i < 4; ++i)
#pragma unroll
        for (int j = 0; j < 3; ++j)
          acc[i][j] = __builtin_amdgcn_mfma_f32_16x16x32_bf16(bf[j], af[i],
                                                              acc[i][j], 0, 0, 0);
      __builtin_amdgcn_s_setprio(0);
    }
  }

  // epilogue: out[b][chan][tok] = resid + acc + bias, 3 x 64-chan slices
  {
    float* tile = (float*)smem;
    const int b = m0 >> 10, tok0 = m0 & (N_ - 1);
#pragma unroll
    for (int sl = 0; sl < 3; ++sl) {
      __syncthreads();
#pragma unroll
      for (int j = 0; j < 3; ++j) {
        const int nl0 = wc * 48 + j * 16 + kq * 4;
        if (((wc * 48 + j * 16) >> 6) == sl) {   // wave-uniform
          const int n = n0 + nl0;
          const f32x4 bv = *(const f32x4*)(bias + n);
#pragma unroll
          for (int i = 0; i < 4; ++i) {
            const int ml = wr * 64 + i * 16 + lr;
            const float* rp = resid + (size_t)(m0 + ml) * C_ + n;
            f32x4 old = *(const f32x4*)rp;
            const f32x4 v = acc[i][j];
#pragma unroll
            for (int r = 0; r < 4; ++r)
              tile[(nl0 - sl * 64 + r) * 132 + ml] = old[r] + v[r] + bv[r];
          }
        }
      }
      __syncthreads();
      const int nl = tid & 63, mc = tid >> 6;   // 64 chans x 8 m-chunks of 16
      float* dst = outp + ((size_t)(b * C_ + n0 + sl * 64 + nl)) * N_ +
                   tok0 + mc * 16;
      const float* src = tile + nl * 132 + mc * 16;
#pragma unroll
      for (int q = 0; q < 4; ++q)
        *(f32x4*)(dst + q * 4) = *(const f32x4*)(src + q * 4);
    }
  }
}

// ---------------------------------------------------------------------------
// Flash attention: 1-D grid 768 blocks, 256 thr, 3 blocks/CU.
// XCD REMAP: g = bid&7 owns heads [12g, 12g+12) x all 8 q-tiles.
// ---------------------------------------------------------------------------
__global__ __launch_bounds__(256, 3) void flash_attn(
    const bf16* __restrict__ Qb, const bf16* __restrict__ Kb,
    const bf16* __restrict__ Vt, bf16* __restrict__ attn) {
  __shared__ __align__(16) bf16 ksm[2][64 * 64];
  __shared__ __align__(16) bf16 vsm[2][64 * 64];
  __shared__ __align__(16) bf16 psm[4][32 * 64];

  const int tid = threadIdx.x, wave = tid >> 6, lane = tid & 63;
  const int lr = lane & 15, kq = lane >> 4;
  const int bid = blockIdx.x;
  const int g = bid & 7, s = bid >> 3;          // s in [0,96)
  const int head = g * 12 + (s % 12);           // XCD g owns 12 heads
  const int qt = s / 12;                        // q-tile 0..7
  const int b = head / NH_, hh = head - b * NH_;
  const int q0 = qt * 128;
  const bf16* Qh = Qb + (size_t)head * (N_ * HD_);
  const bf16* Kh = Kb + (size_t)head * (N_ * HD_);
  const bf16* Vh = Vt + (size_t)head * (HD_ * N_);
  char* pw = (char*)&psm[wave][0];

  bf16x8 qf[2][2];
#pragma unroll
  for (int j = 0; j < 2; ++j)
#pragma unroll
    for (int kh = 0; kh < 2; ++kh)
      qf[j][kh] = *(const bf16x8*)(Qh +
                                   (size_t)(q0 + wave * 32 + j * 16 + lr) * HD_ +
                                   kh * 32 + kq * 8);

  f32x4 o[4][2];
#pragma unroll
  for (int i = 0; i < 4; i++)
#pragma unroll
    for (int j = 0; j < 2; j++) o[i][j] = (f32x4){0.f, 0.f, 0.f, 0.f};
  float mprev[2] = {-1e30f, -1e30f}, lacc[2] = {0.f, 0.f};

  auto stage = [&](int t, int bi) {
#pragma unroll
    for (int it = 0; it < 2; ++it) {
      int s2 = it * 256 + tid;
      int r = s2 >> 3, seg = (s2 & 7) ^ (r & 7);
      gload_lds16(Kh + (size_t)(t * 64 + r) * HD_ + seg * 8,
                  (char*)ksm[bi] + (it * 256 + wave * 64) * 16);
    }
#pragma unroll
    for (int it = 0; it < 2; ++it) {
      int s2 = it * 256 + tid;
      int r = s2 >> 3, seg = (s2 & 7) ^ (r & 7);
      gload_lds16(Vh + (size_t)r * N_ + t * 64 + seg * 8,
                  (char*)vsm[bi] + (it * 256 + wave * 64) * 16);
    }
  };

  stage(0, 0);

  for (int t = 0; t < 16; ++t) {
    const int bi = t & 1;
    __syncthreads();
    if (t < 15) stage(t + 1, bi ^ 1);

    f32x4 sacc[4][2];
#pragma unroll
    for (int i = 0; i < 4; ++i) {
#pragma unroll
      for (int j = 0; j < 2; ++j) sacc[i][j] = (f32x4){0.f, 0.f, 0.f, 0.f};
      int row = i * 16 + lr;
      bf16x8 kf0 = *(const bf16x8*)((char*)ksm[bi] + row * 128 +
                                    ((kq ^ (row & 7)) * 16));
      bf16x8 kf1 = *(const bf16x8*)((char*)ksm[bi] + row * 128 +
                                    (((4 + kq) ^ (row & 7)) * 16));
#pragma unroll
      for (int j = 0; j < 2; ++j) {
        sacc[i][j] = __builtin_amdgcn_mfma_f32_16x16x32_bf16(kf0, qf[j][0],
                                                             sacc[i][j], 0, 0, 0);
        sacc[i][j] = __builtin_amdgcn_mfma_f32_16x16x32_bf16(kf1, qf[j][1],
                                                             sacc[i][j], 0, 0, 0);
      }
    }

#pragma unroll
    for (int j = 0; j < 2; ++j) {
      float mx = -1e30f;
#pragma unroll
      for (int i = 0; i < 4; ++i)
#pragma unroll
        for (int r = 0; r < 4; ++r) mx = fmaxf(mx, sacc[i][j][r]);
      mx = fmaxf(mx, __shfl_xor(mx, 16));
      mx = fmaxf(mx, __shfl_xor(mx, 32));
      float mnew = fmaxf(mprev[j], mx);
      float alpha = __builtin_amdgcn_exp2f((mprev[j] - mnew) * FA_C);
      mprev[j] = mnew;
      float rs = 0.f;
      const int prow = j * 16 + lr;
#pragma unroll
      for (int i = 0; i < 4; ++i) {
        float p0 = __builtin_amdgcn_exp2f((sacc[i][j][0] - mnew) * FA_C);
        float p1 = __builtin_amdgcn_exp2f((sacc[i][j][1] - mnew) * FA_C);
        float p2 = __builtin_amdgcn_exp2f((sacc[i][j][2] - mnew) * FA_C);
        float p3 = __builtin_amdgcn_exp2f((sacc[i][j][3] - mnew) * FA_C);
        rs += (p0 + p1) + (p2 + p3);
        bf16x4 pk = {(bf16)p0, (bf16)p1, (bf16)p2, (bf16)p3};
        int c = i * 2 + (kq >> 1);
        *(bf16x4*)(pw + prow * 128 + ((c ^ (prow & 7)) * 16) + (kq & 1) * 8) = pk;
      }
      rs += __shfl_xor(rs, 16);
      rs += __shfl_xor(rs, 32);
      lacc[j] = lacc[j] * alpha + rs;
#pragma unroll
      for (int i = 0; i < 4; ++i) {
        o[i][j][0] *= alpha; o[i][j][1] *= alpha;
        o[i][j][2] *= alpha; o[i][j][3] *= alpha;
      }
    }

#pragma unroll
    for (int k0c = 0; k0c < 2; ++k0c) {
      bf16x8 pf[2];
#pragma unroll
      for (int j = 0; j < 2; ++j) {
        int prow = j * 16 + lr, c = k0c * 4 + kq;
        pf[j] = *(const bf16x8*)(pw + prow * 128 + ((c ^ (prow & 7)) * 16));
      }
#pragma unroll
      for (int i = 0; i < 4; ++i) {
        int d = i * 16 + lr, c = k0c * 4 + kq;
        bf16x8 vf = *(const bf16x8*)((char*)vsm[bi] + d * 128 +
                                     ((c ^ (d & 7)) * 16));
#pragma unroll
        for (int j = 0; j < 2; ++j)
          o[i][j] = __builtin_amdgcn_mfma_f32_16x16x32_bf16(vf, pf[j], o[i][j],
                                                            0, 0, 0);
      }
    }
  }

#pragma unroll
  for (int j = 0; j < 2; ++j) {
    float inv = 1.0f / lacc[j];
    int tok = q0 + wave * 32 + j * 16 + lr;
    bf16* op = attn + ((size_t)(b * N_ + tok)) * C_ + hh * HD_;
#pragma unroll
    for (int i = 0; i < 4; ++i) {
      bf16x4 pk = {(bf16)(o[i][j][0] * inv), (bf16)(o[i][j][1] * inv),
                   (bf16)(o[i][j][2] * inv), (bf16)(o[i][j][3] * inv)};
      *(bf16x4*)(op + i * 16 + kq * 4) = pk;
    }
  }
}

// ---------------------------------------------------------------------------
__global__ __launch_bounds__(256) void cast_all(
    const float* __restrict__ a, int na, const float* __restrict__ b, int nb,
    const float* __restrict__ c, int nc, const float* __restrict__ d,
    bf16* __restrict__ dst) {
  int i = (blockIdx.x * 256 + threadIdx.x) * 4;
  const float* src;
  int off;
  if (i < na) { src = a; off = i; }
  else if (i < na + nb) { src = b; off = i - na; }
  else if (i < na + nb + nc) { src = c; off = i - na - nb; }
  else { src = d; off = i - na - nb - nc; }
  float4 v = *(const float4*)(src + off);
  bf16x4 o = {(bf16)v.x, (bf16)v.y, (bf16)v.z, (bf16)v.w};
  *(bf16x4*)(dst + i) = o;
}

// LayerNorm over C=768, fp32 in, bf16 out (used for ln2)
__global__ __launch_bounds__(256) void ln_bf16(const float* __restrict__ t,
                                               const float* __restrict__ g,
                                               const float* __restrict__ be,
                                               bf16* __restrict__ out) {
  int row = blockIdx.x, tid = threadIdx.x;
  const float* p = t + (size_t)row * C_;
  float v0 = p[tid], v1 = p[tid + 256], v2 = p[tid + 512];
  __shared__ float rs[256], rq[256];
  rs[tid] = v0 + v1 + v2;
  rq[tid] = v0 * v0 + v1 * v1 + v2 * v2;
  __syncthreads();
  for (int off = 128; off; off >>= 1) {
    if (tid < off) {
      rs[tid] += rs[tid + off];
      rq[tid] += rq[tid + off];
    }
    __syncthreads();
  }
  float mu = rs[0] * (1.f / C_);
  float var = rq[0] * (1.f / C_) - mu * mu;
  float rstd = rsqrtf(var + 1e-5f);
  bf16* q = out + (size_t)row * C_;
  q[tid] = (bf16)((v0 - mu) * rstd * g[tid] + be[tid]);
  q[tid + 256] = (bf16)((v1 - mu) * rstd * g[tid + 256] + be[tid + 256]);
  q[tid + 512] = (bf16)((v2 - mu) * rstd * g[tid + 512] + be[tid + 512]);
}

// ---------------------------------------------------------------------------
extern "C" void kernel_launch(void* const* d_in, const int* in_sizes, int n_in,
                              void* d_out, int out_size, void* d_ws,
                              size_t ws_size, hipStream_t stream) {
  (void)in_sizes; (void)n_in; (void)out_size; (void)ws_size;
  const float* x      = (const float*)d_in[0];
  const float* conv_w = (const float*)d_in[1];
  const float* conv_b = (const float*)d_in[2];
  const float* ln1_g  = (const float*)d_in[3];
  const float* ln1_b  = (const float*)d_in[4];
  const float* qkv_w  = (const float*)d_in[5];
  const float* proj_w = (const float*)d_in[6];
  const float* proj_b = (const float*)d_in[7];
  const float* ln2_g  = (const float*)d_in[8];
  const float* ln2_b  = (const float*)d_in[9];
  const float* fc1_w  = (const float*)d_in[10];
  const float* fc1_b  = (const float*)d_in[11];
  const float* fc2_w  = (const float*)d_in[12];
  const float* fc2_b  = (const float*)d_in[13];
  float* out = (float*)d_out;

  char* w = (char*)d_ws;
  auto carve = [&](size_t bytes) {
    char* p = w;
    w += (bytes + 255) & ~(size_t)255;
    return p;
  };
  bf16* hid   = (bf16*)carve((size_t)NTOK * HID_ * 2);
  float* t0   = (float*)carve((size_t)NTOK * C_ * 4);
  bf16* lnout = (bf16*)carve((size_t)NTOK * C_ * 2);
  bf16* wq    = (bf16*)carve((size_t)3 * C_ * C_ * 2);
  bf16* wp    = (bf16*)carve((size_t)C_ * C_ * 2);
  bf16* w1    = (bf16*)carve((size_t)HID_ * C_ * 2);
  bf16* w2    = (bf16*)carve((size_t)C_ * HID_ * 2);
  bf16* Qb    = (bf16*)carve((size_t)NHEADS * N_ * HD_ * 2);
  bf16* Kb    = (bf16*)carve((size_t)NHEADS * N_ * HD_ * 2);
  bf16* Vt    = (bf16*)carve((size_t)NHEADS * HD_ * N_ * 2);
  bf16* attn  = (bf16*)carve((size_t)NTOK * C_ * 2);

  const int na = 3 * C_ * C_, nb = C_ * C_, nc = HID_ * C_, nd = C_ * HID_;
  cast_all<<<(na + nb + nc + nd) / 1024, 256, 0, stream>>>(
      qkv_w, na, proj_w, nb, fc1_w, nc, fc2_w, wq);

  // fused depthwise-conv + residual + LN1: writes t0 (f32) AND lnout (bf16)
  conv_ln<<<256, 256, 0, stream>>>(x, conv_w, conv_b, ln1_g, ln1_b, t0, lnout);

  // QKV: gemm_pipe 128x192 tribuf, 64m x 12n = 768 blocks = 3 exact rounds
  gemm_pipe<0><<<768, 512, 0, stream>>>(lnout, wq, 768, 768, 768, 12,
                                        Qb, Kb, Vt, nullptr, nullptr);

  // flash: 1-D grid, head-per-XCD remap (12 heads x 8 q-tiles per XCD)
  flash_attn<<<768, 256, 0, stream>>>(Qb, Kb, Vt, attn);

  // proj: gemm_pipe 128x192 tribuf, 64m x 4n = 256 blocks = 1 exact round
  gemm_pipe<1><<<256, 512, 0, stream>>>(attn, wp, 768, 768, 768, 4,
                                        nullptr, nullptr, nullptr, t0, proj_b);
  ln_bf16<<<NTOK, 256, 0, stream>>>(t0, ln2_g, ln2_b, lnout);
  // fc1: R9-best 256x192 4-phase (512 blocks = 2 exact rounds)
  gemm_fc1<<<512, 512, 0, stream>>>(lnout, w1, fc1_b, hid, 768, 768, 768,
                                    16, 4, HID_);
  // fc2: R10-best 128x192 tribuf (256 blocks = 1 round), NCHW epilogue
  gemm_fc2<<<256, 512, 0, stream>>>(hid, w2, fc2_b, t0, out, 3072, 3072, 3072);
}

// Round 11
// 374.126 us; speedup vs baseline: 1.3308x; 1.3308x over previous
//
#include <hip/hip_runtime.h>
#include <math.h>

// ---------------------------------------------------------------------------
// SABlock: x[B,C,H,W] -> depthwise3x3+res -> [B,N,C]: LN1 -> QKV -> flash-MHA
//          -> proj +res -> LN2 -> FC1 -> GELU -> FC2 -> +res -> [B,C,H,W]
// R17: REVERT of R16's conv+LN fusion (173us: 1 block/CU + 4 waves ->
// latency trap; 590K LDS bank conflicts; occupancy 8.7%). Restores the
// R15 best-measured config: conv_pe_t (6144 blocks) + ln_bf16 for ln1;
// qkv/proj = gemm_pipe tribuf; fc1 = R9 4-phase; fc2 = R10 tribuf;
// flash = head-per-XCD remap. All kernels at measured-best forms.
// ---------------------------------------------------------------------------

typedef __bf16 bf16;
typedef __attribute__((ext_vector_type(8))) __bf16 bf16x8;
typedef __attribute__((ext_vector_type(4))) __bf16 bf16x4;
typedef __attribute__((ext_vector_type(4))) float f32x4;

#define B_   8
#define C_   768
#define N_   1024
#define NH_  12
#define HD_  64
#define HID_ 3072
#define NTOK   (B_ * N_)     // 8192
#define NHEADS (B_ * NH_)    // 96
#define FA_C   0.1803368801111601f  // 0.125 * log2(e)

__device__ __forceinline__ void gload_lds16(const void* g, void* l) {
  __builtin_amdgcn_global_load_lds(
      (__attribute__((address_space(1))) void*)(void*)g,
      (__attribute__((address_space(3))) void*)l, 16, 0, 0);
}

__device__ __forceinline__ float gelu1(float x) {
  // tanh-form GELU via exp2; |err| well under bf16 noise (verified R4/R5)
  float u = 0.7978845608028654f * x * (1.0f + 0.044715f * x * x);
  float e = __builtin_amdgcn_exp2f(u * 2.885390081777927f);  // exp(2u)
  float th = 1.0f - 2.0f * __builtin_amdgcn_rcpf(e + 1.0f);
  return 0.5f * x * (1.0f + th);
}

// counted-vmcnt phase boundary: vmcnt+lgkm BEFORE the raw barrier.
#define PIPE_SYNC(N)                                              \
  do {                                                            \
    asm volatile("s_waitcnt vmcnt(" #N ") lgkmcnt(0)" ::: "memory"); \
    __builtin_amdgcn_sched_barrier(0);                            \
    __builtin_amdgcn_s_barrier();                                 \
    __builtin_amdgcn_sched_barrier(0);                            \
    asm volatile("" ::: "memory");                                \
  } while (0)

// ---------------------------------------------------------------------------
// gemm_pipe<EPI>: 128x192-tile pipelined B^T GEMM (fc2-tribuf structure).
// 512 thr = 8 waves (2 Wm x 4 Wc); wave tile 64x48 (4 m-frags x 3 n-frags).
// LDS: 3 buffers x (A 16KB + B 24KB) = 120 KB; prefetch distance 2 K-tiles;
// one PIPE_SYNC(5) per K-tile (never drains mid-loop). Last tile peeled.
// Swizzle: chunk slot = c ^ (row&7) (0 bank conflicts). REMAP: bid&7 = XCD
// owns 8 m-tiles x all ntiles n-tiles.
// EPI 0: QKV scatter -- n0<768 -> Q, <1536 -> K (per-head bf16x4 stores,
//        [head][tok][d]); else V via 192x128 swizzled LDS bounce ->
//        coalesced V^T bf16x8 rows [head][d][tok].
// EPI 1: proj: resid float4 RMW += acc + bias.
// ---------------------------------------------------------------------------
template <int EPI>
__global__ __launch_bounds__(512) void gemm_pipe(
    const bf16* __restrict__ A, const bf16* __restrict__ Bw, int K, int lda,
    int ldb, int ntiles, bf16* __restrict__ o0, bf16* __restrict__ o1,
    bf16* __restrict__ o2, float* __restrict__ resid,
    const float* __restrict__ bias) {
  __shared__ __align__(16) char smem[122880];
  const int tid = threadIdx.x;
  const int wave = tid >> 6, lane = tid & 63;
  const int wr = wave & 1, wc = wave >> 1;
  const int lr = lane & 15, kq = lane >> 4;

  const int bid = blockIdx.x;
  const int g = bid & 7, s = bid >> 3;
  const int ms = s / ntiles;
  const int m0 = (g * 8 + ms) * 128;
  const int n0 = (s - ms * ntiles) * 192;

  f32x4 acc[4][3];
#pragma unroll
  for (int i = 0; i < 4; ++i)
#pragma unroll
    for (int j = 0; j < 3; ++j) acc[i][j] = (f32x4){0.f, 0.f, 0.f, 0.f};

  const bf16* pa[2];
  const bf16* pb[3];
  int da[2], db[3];
#pragma unroll
  for (int c = 0; c < 2; ++c) {
    const int sidx = c * 512 + tid;
    const int r = sidx >> 3, seg = (sidx & 7) ^ (r & 7);
    pa[c] = A + (size_t)(m0 + r) * lda + seg * 8;
    da[c] = sidx * 16;
  }
#pragma unroll
  for (int c = 0; c < 3; ++c) {
    const int sidx = c * 512 + tid;
    const int r = sidx >> 3, seg = (sidx & 7) ^ (r & 7);
    pb[c] = Bw + (size_t)(n0 + r) * ldb + seg * 8;
    db[c] = 16384 + sidx * 16;
  }

  const int NT = K >> 6;

  // prologue: stage tiles 0 (buf0) and 1 (buf1); 10 loads in flight
#pragma unroll
  for (int tt = 0; tt < 2; ++tt) {
    char* wb = smem + tt * 40960;
    gload_lds16(pb[0], wb + db[0]);
    gload_lds16(pb[1], wb + db[1]);
    gload_lds16(pb[2], wb + db[2]);
    gload_lds16(pa[0], wb + da[0]);
    gload_lds16(pa[1], wb + da[1]);
    pb[0] += 64; pb[1] += 64; pb[2] += 64; pa[0] += 64; pa[1] += 64;
  }

  int cur = 0;
  for (int t = 0; t < NT - 1; ++t) {
    const char* rb = smem + cur * 40960;
    PIPE_SYNC(5);
    if (t < NT - 2) {
      int wi = cur + 2; if (wi >= 3) wi -= 3;
      char* wb = smem + wi * 40960;
      gload_lds16(pb[0], wb + db[0]); pb[0] += 64;
      gload_lds16(pb[1], wb + db[1]); pb[1] += 64;
      gload_lds16(pb[2], wb + db[2]); pb[2] += 64;
      gload_lds16(pa[0], wb + da[0]); pa[0] += 64;
      gload_lds16(pa[1], wb + da[1]); pa[1] += 64;
    }
    bf16x8 af[4], bf[3];
    // ---- k-half 0
#pragma unroll
    for (int i = 0; i < 4; ++i) {
      const int r = wr * 64 + i * 16 + lr;
      af[i] = *(const bf16x8*)(rb + (r * 8 + (kq ^ (r & 7))) * 16);
    }
#pragma unroll
    for (int j = 0; j < 3; ++j) {
      const int r = wc * 48 + j * 16 + lr;
      bf[j] = *(const bf16x8*)(rb + 16384 + (r * 8 + (kq ^ (r & 7))) * 16);
    }
    __builtin_amdgcn_s_setprio(1);
#pragma unroll
    for (int i = 0; i < 4; ++i)
#pragma unroll
      for (int j = 0; j < 3; ++j)
        acc[i][j] = __builtin_amdgcn_mfma_f32_16x16x32_bf16(bf[j], af[i],
                                                            acc[i][j], 0, 0, 0);
    __builtin_amdgcn_s_setprio(0);
    // ---- k-half 1
#pragma unroll
    for (int i = 0; i < 4; ++i) {
      const int r = wr * 64 + i * 16 + lr;
      af[i] = *(const bf16x8*)(rb + (r * 8 + ((4 + kq) ^ (r & 7))) * 16);
    }
#pragma unroll
    for (int j = 0; j < 3; ++j) {
      const int r = wc * 48 + j * 16 + lr;
      bf[j] = *(const bf16x8*)(rb + 16384 + (r * 8 + ((4 + kq) ^ (r & 7))) * 16);
    }
    __builtin_amdgcn_s_setprio(1);
#pragma unroll
    for (int i = 0; i < 4; ++i)
#pragma unroll
      for (int j = 0; j < 3; ++j)
        acc[i][j] = __builtin_amdgcn_mfma_f32_16x16x32_bf16(bf[j], af[i],
                                                            acc[i][j], 0, 0, 0);
    __builtin_amdgcn_s_setprio(0);
    if (++cur == 3) cur = 0;
  }

  {  // ---- last K-tile, peeled: full drain, no staging
    const char* rb = smem + cur * 40960;
    bf16x8 af[4], bf[3];
    PIPE_SYNC(0);
#pragma unroll
    for (int kh = 0; kh < 2; ++kh) {
      const int c0 = kh * 4 + kq;
#pragma unroll
      for (int i = 0; i < 4; ++i) {
        const int r = wr * 64 + i * 16 + lr;
        af[i] = *(const bf16x8*)(rb + (r * 8 + (c0 ^ (r & 7))) * 16);
      }
#pragma unroll
      for (int j = 0; j < 3; ++j) {
        const int r = wc * 48 + j * 16 + lr;
        bf[j] = *(const bf16x8*)(rb + 16384 + (r * 8 + (c0 ^ (r & 7))) * 16);
      }
      __builtin_amdgcn_s_setprio(1);
#pragma unroll
      for (int i = 0; i < 4; ++i)
#pragma unroll
        for (int j = 0; j < 3; ++j)
          acc[i][j] = __builtin_amdgcn_mfma_f32_16x16x32_bf16(bf[j], af[i],
                                                              acc[i][j], 0, 0, 0);
      __builtin_amdgcn_s_setprio(0);
    }
  }

  if constexpr (EPI == 0) {
    const int b = m0 >> 10, tok0 = m0 & (N_ - 1);
    if (n0 < 2 * C_) {
      // Q or K: vector bf16x4 stores, [head][tok][d]
      const int sdx = n0 >= C_ ? 1 : 0;
      bf16* dst = sdx ? o1 : o0;
      const int nb = n0 - sdx * C_;
#pragma unroll
      for (int j = 0; j < 3; ++j) {
        const int rem = nb + wc * 48 + j * 16 + kq * 4;
        const int h = rem >> 6, d = rem & 63;
        bf16* hp = dst + (size_t)(b * NH_ + h) * (N_ * HD_) + d;
#pragma unroll
        for (int i = 0; i < 4; ++i) {
          const int tok = tok0 + wr * 64 + i * 16 + lr;
          const f32x4 v = acc[i][j];
          bf16x4 pk = {(bf16)v[0], (bf16)v[1], (bf16)v[2], (bf16)v[3]};
          *(bf16x4*)(hp + (size_t)tok * HD_) = pk;
        }
      }
    } else {
      // V: swizzled LDS bounce (192 rows x 128 toks) -> V^T bf16x8 rows
      bf16* tile = (bf16*)smem;
#pragma unroll
      for (int i = 0; i < 4; ++i) {
        const int ml = wr * 64 + i * 16 + lr;
        const int mc = ml >> 3, mo = ml & 7;
#pragma unroll
        for (int j = 0; j < 3; ++j) {
          const f32x4 v = acc[i][j];
#pragma unroll
          for (int r = 0; r < 4; ++r) {
            const int nl = wc * 48 + j * 16 + kq * 4 + r;
            *(bf16*)((char*)tile + nl * 256 + ((mc ^ (nl & 15)) * 16) + mo * 2) =
                (bf16)v[r];
          }
        }
      }
      __syncthreads();
      const int vbase = n0 - 2 * C_;
#pragma unroll
      for (int c = 0; c < 6; ++c) {
        const int idx = c * 512 + tid;
        const int row = idx >> 4, ch = idx & 15;
        bf16x8 val = *(const bf16x8*)((char*)tile + row * 256 +
                                      ((ch ^ (row & 15)) * 16));
        const int vb = vbase + row;
        bf16* dstp = o2 + ((size_t)(b * NH_ + (vb >> 6)) * HD_ + (vb & 63)) * N_ +
                     tok0 + ch * 8;
        *(bf16x8*)dstp = val;
      }
    }
  } else {
    // proj: resid float4 RMW += acc + bias
#pragma unroll
    for (int j = 0; j < 3; ++j) {
      const int n = n0 + wc * 48 + j * 16 + kq * 4;
      const f32x4 bv = *(const f32x4*)(bias + n);
#pragma unroll
      for (int i = 0; i < 4; ++i) {
        const int m = m0 + wr * 64 + i * 16 + lr;
        float* rp = resid + (size_t)m * C_ + n;
        f32x4 old = *(const f32x4*)rp;
        const f32x4 v = acc[i][j];
        f32x4 nw = {old[0] + v[0] + bv[0], old[1] + v[1] + bv[1],
                    old[2] + v[2] + bv[2], old[3] + v[3] + bv[3]};
        *(f32x4*)rp = nw;
      }
    }
  }
}

// ---------------------------------------------------------------------------
// fc1: 256x192-tile pipelined B^T GEMM + GELU epilogue. (R9-best, 56.1us.)
// Grid 512 = 32 m-tiles x 16 n-tiles = EXACTLY 2 rounds at 1 block/CU.
// ---------------------------------------------------------------------------
__global__ __launch_bounds__(512) void gemm_fc1(
    const bf16* __restrict__ A, const bf16* __restrict__ Bw,
    const float* __restrict__ bias, bf16* __restrict__ outp,
    int K, int lda, int ldb, int ntiles, int mtpx, int ldo) {
  __shared__ __align__(16) char smem[114688];
  const int tid = threadIdx.x;
  const int wave = tid >> 6, lane = tid & 63;
  const int wr = wave & 1, wc = wave >> 1;
  const int lr = lane & 15, kq = lane >> 4;

  const int bid = blockIdx.x;
  const int g = bid & 7, s = bid >> 3;
  const int ms = s / ntiles;
  const int m0 = (g * mtpx + ms) * 256;
  const int n0 = (s - ms * ntiles) * 192;

  f32x4 acc[8][3];
#pragma unroll
  for (int i = 0; i < 8; ++i)
#pragma unroll
    for (int j = 0; j < 3; ++j) acc[i][j] = (f32x4){0.f, 0.f, 0.f, 0.f};

  const bf16* pa[4];
  const bf16* pb[3];
  int da[4], db[3];
#pragma unroll
  for (int c = 0; c < 4; ++c) {
    const int sidx = c * 512 + tid;
    const int r = sidx >> 3, seg = (sidx & 7) ^ (r & 7);
    pa[c] = A + (size_t)(m0 + r) * lda + seg * 8;
    da[c] = sidx * 16;
  }
#pragma unroll
  for (int c = 0; c < 3; ++c) {
    const int sidx = c * 512 + tid;
    const int r = sidx >> 3, seg = (sidx & 7) ^ (r & 7);
    pb[c] = Bw + (size_t)(n0 + r) * ldb + seg * 8;
    db[c] = 32768 + sidx * 16;
  }

  const int NT = K >> 6;

  gload_lds16(pb[0], smem + db[0]);
  gload_lds16(pb[1], smem + db[1]);
  gload_lds16(pb[2], smem + db[2]);
  gload_lds16(pa[0], smem + da[0]);
  gload_lds16(pa[1], smem + da[1]);
  gload_lds16(pa[2], smem + da[2]);
  gload_lds16(pa[3], smem + da[3]);
#pragma unroll
  for (int c = 0; c < 4; ++c) pa[c] += 64;
#pragma unroll
  for (int c = 0; c < 3; ++c) pb[c] += 64;

  for (int t = 0; t < NT - 1; ++t) {
    const char* rb = smem + (t & 1) * 57344;
    char* wb = smem + ((t & 1) ^ 1) * 57344;
    bf16x8 af[4], bf0[3], bf1[3];

    // ---- ph0: k0 x m-rows[0..63 of half] + all B k0; stage B0,B1
    PIPE_SYNC(1);
#pragma unroll
    for (int i = 0; i < 4; ++i) {
      const int r = wr * 128 + i * 16 + lr;
      af[i] = *(const bf16x8*)(rb + (r * 8 + (kq ^ (r & 7))) * 16);
    }
#pragma unroll
    for (int j = 0; j < 3; ++j) {
      const int r = wc * 48 + j * 16 + lr;
      bf0[j] = *(const bf16x8*)(rb + 32768 + (r * 8 + (kq ^ (r & 7))) * 16);
    }
    gload_lds16(pb[0], wb + db[0]); pb[0] += 64;
    gload_lds16(pb[1], wb + db[1]); pb[1] += 64;
    __builtin_amdgcn_s_setprio(1);
#pragma unroll
    for (int i = 0; i < 4; ++i)
#pragma unroll
      for (int j = 0; j < 3; ++j)
        acc[i][j] = __builtin_amdgcn_mfma_f32_16x16x32_bf16(bf0[j], af[i],
                                                            acc[i][j], 0, 0, 0);
    __builtin_amdgcn_s_setprio(0);

    // ---- ph1: k0 x m-rows[64..127 of half]; stage B2,A0
    PIPE_SYNC(2);
#pragma unroll
    for (int i = 0; i < 4; ++i) {
      const int r = wr * 128 + 64 + i * 16 + lr;
      af[i] = *(const bf16x8*)(rb + (r * 8 + (kq ^ (r & 7))) * 16);
    }
    gload_lds16(pb[2], wb + db[2]); pb[2] += 64;
    gload_lds16(pa[0], wb + da[0]); pa[0] += 64;
    __builtin_amdgcn_s_setprio(1);
#pragma unroll
    for (int i = 0; i < 4; ++i)
#pragma unroll
      for (int j = 0; j < 3; ++j)
        acc[4 + i][j] = __builtin_amdgcn_mfma_f32_16x16x32_bf16(
            bf0[j], af[i], acc[4 + i][j], 0, 0, 0);
    __builtin_amdgcn_s_setprio(0);

    // ---- ph2: k1 x m-rows[0..63 of half] + all B k1; stage A1,A2
    PIPE_SYNC(4);
#pragma unroll
    for (int i = 0; i < 4; ++i) {
      const int r = wr * 128 + i * 16 + lr;
      af[i] = *(const bf16x8*)(rb + (r * 8 + ((4 + kq) ^ (r & 7))) * 16);
    }
#pragma unroll
    for (int j = 0; j < 3; ++j) {
      const int r = wc * 48 + j * 16 + lr;
      bf1[j] = *(const bf16x8*)(rb + 32768 + (r * 8 + ((4 + kq) ^ (r & 7))) * 16);
    }
    gload_lds16(pa[1], wb + da[1]); pa[1] += 64;
    gload_lds16(pa[2], wb + da[2]); pa[2] += 64;
    __builtin_amdgcn_s_setprio(1);
#pragma unroll
    for (int i = 0; i < 4; ++i)
#pragma unroll
      for (int j = 0; j < 3; ++j)
        acc[i][j] = __builtin_amdgcn_mfma_f32_16x16x32_bf16(bf1[j], af[i],
                                                            acc[i][j], 0, 0, 0);
    __builtin_amdgcn_s_setprio(0);

    // ---- ph3: k1 x m-rows[64..127 of half]; stage A3
    PIPE_SYNC(6);
#pragma unroll
    for (int i = 0; i < 4; ++i) {
      const int r = wr * 128 + 64 + i * 16 + lr;
      af[i] = *(const bf16x8*)(rb + (r * 8 + ((4 + kq) ^ (r & 7))) * 16);
    }
    gload_lds16(pa[3], wb + da[3]); pa[3] += 64;
    __builtin_amdgcn_s_setprio(1);
#pragma unroll
    for (int i = 0; i < 4; ++i)
#pragma unroll
      for (int j = 0; j < 3; ++j)
        acc[4 + i][j] = __builtin_amdgcn_mfma_f32_16x16x32_bf16(
            bf1[j], af[i], acc[4 + i][j], 0, 0, 0);
    __builtin_amdgcn_s_setprio(0);
  }

  {  // ---- last K-tile, peeled: full drain, no barriers, no staging
    const char* rb = smem + ((NT - 1) & 1) * 57344;
    bf16x8 af[4], bf0[3], bf1[3];
    PIPE_SYNC(0);
#pragma unroll
    for (int j = 0; j < 3; ++j) {
      const int r = wc * 48 + j * 16 + lr;
      bf0[j] = *(const bf16x8*)(rb + 32768 + (r * 8 + (kq ^ (r & 7))) * 16);
      bf1[j] = *(const bf16x8*)(rb + 32768 + (r * 8 + ((4 + kq) ^ (r & 7))) * 16);
    }
    __builtin_amdgcn_s_setprio(1);
#pragma unroll
    for (int half = 0; half < 2; ++half) {
#pragma unroll
      for (int i = 0; i < 4; ++i) {
        const int r = wr * 128 + half * 64 + i * 16 + lr;
        af[i] = *(const bf16x8*)(rb + (r * 8 + (kq ^ (r & 7))) * 16);
      }
#pragma unroll
      for (int i = 0; i < 4; ++i)
#pragma unroll
        for (int j = 0; j < 3; ++j)
          acc[half * 4 + i][j] = __builtin_amdgcn_mfma_f32_16x16x32_bf16(
              bf0[j], af[i], acc[half * 4 + i][j], 0, 0, 0);
#pragma unroll
      for (int i = 0; i < 4; ++i) {
        const int r = wr * 128 + half * 64 + i * 16 + lr;
        af[i] = *(const bf16x8*)(rb + (r * 8 + ((4 + kq) ^ (r & 7))) * 16);
      }
#pragma unroll
      for (int i = 0; i < 4; ++i)
#pragma unroll
        for (int j = 0; j < 3; ++j)
          acc[half * 4 + i][j] = __builtin_amdgcn_mfma_f32_16x16x32_bf16(
              bf1[j], af[i], acc[half * 4 + i][j], 0, 0, 0);
    }
    __builtin_amdgcn_s_setprio(0);
  }

  // epilogue: GELU(acc + bias) -> bf16
#pragma unroll
  for (int j = 0; j < 3; ++j) {
    const int n = n0 + wc * 48 + j * 16 + kq * 4;
    const f32x4 bv = *(const f32x4*)(bias + n);
#pragma unroll
    for (int i = 0; i < 8; ++i) {
      const int m = m0 + wr * 128 + i * 16 + lr;
      const f32x4 v = acc[i][j];
      bf16x4 pk = {(bf16)gelu1(v[0] + bv[0]), (bf16)gelu1(v[1] + bv[1]),
                   (bf16)gelu1(v[2] + bv[2]), (bf16)gelu1(v[3] + bv[3])};
      *(bf16x4*)(outp + (size_t)m * ldo + n) = pk;
    }
  }
}

// ---------------------------------------------------------------------------
// fc2: 128x192-tile pipelined B^T GEMM, K=3072 (48 tiles), NCHW epilogue.
// (R10 best-known form: tribuf, distance-2 prefetch, ONE PIPE_SYNC(5) per
// K-tile.) Grid 256 = 64m x 4n = exactly ONE round.
// ---------------------------------------------------------------------------
__global__ __launch_bounds__(512) void gemm_fc2(
    const bf16* __restrict__ A, const bf16* __restrict__ Bw,
    const float* __restrict__ bias, const float* __restrict__ resid,
    float* __restrict__ outp, int K, int lda, int ldb) {
  __shared__ __align__(16) char smem[122880];
  const int tid = threadIdx.x;
  const int wave = tid >> 6, lane = tid & 63;
  const int wr = wave & 1, wc = wave >> 1;
  const int lr = lane & 15, kq = lane >> 4;

  const int bid = blockIdx.x;
  const int g = bid & 7, s = bid >> 3;
  const int ms = s >> 2;                 // 0..7
  const int m0 = (g * 8 + ms) * 128;
  const int n0 = (s & 3) * 192;

  f32x4 acc[4][3];
#pragma unroll
  for (int i = 0; i < 4; ++i)
#pragma unroll
    for (int j = 0; j < 3; ++j) acc[i][j] = (f32x4){0.f, 0.f, 0.f, 0.f};

  const bf16* pa[2];
  const bf16* pb[3];
  int da[2], db[3];
#pragma unroll
  for (int c = 0; c < 2; ++c) {
    const int sidx = c * 512 + tid;
    const int r = sidx >> 3, seg = (sidx & 7) ^ (r & 7);
    pa[c] = A + (size_t)(m0 + r) * lda + seg * 8;
    da[c] = sidx * 16;
  }
#pragma unroll
  for (int c = 0; c < 3; ++c) {
    const int sidx = c * 512 + tid;
    const int r = sidx >> 3, seg = (sidx & 7) ^ (r & 7);
    pb[c] = Bw + (size_t)(n0 + r) * ldb + seg * 8;
    db[c] = 16384 + sidx * 16;
  }

  const int NT = K >> 6;  // 48

#pragma unroll
  for (int tt = 0; tt < 2; ++tt) {
    char* wb = smem + tt * 40960;
    gload_lds16(pb[0], wb + db[0]);
    gload_lds16(pb[1], wb + db[1]);
    gload_lds16(pb[2], wb + db[2]);
    gload_lds16(pa[0], wb + da[0]);
    gload_lds16(pa[1], wb + da[1]);
    pb[0] += 64; pb[1] += 64; pb[2] += 64; pa[0] += 64; pa[1] += 64;
  }

  int cur = 0;
  for (int t = 0; t < NT - 1; ++t) {
    const char* rb = smem + cur * 40960;
    PIPE_SYNC(5);
    if (t < NT - 2) {
      int wi = cur + 2; if (wi >= 3) wi -= 3;
      char* wb = smem + wi * 40960;
      gload_lds16(pb[0], wb + db[0]); pb[0] += 64;
      gload_lds16(pb[1], wb + db[1]); pb[1] += 64;
      gload_lds16(pb[2], wb + db[2]); pb[2] += 64;
      gload_lds16(pa[0], wb + da[0]); pa[0] += 64;
      gload_lds16(pa[1], wb + da[1]); pa[1] += 64;
    }
    bf16x8 af[4], bf[3];
    // ---- k-half 0
#pragma unroll
    for (int i = 0; i < 4; ++i) {
      const int r = wr * 64 + i * 16 + lr;
      af[i] = *(const bf16x8*)(rb + (r * 8 + (kq ^ (r & 7))) * 16);
    }
#pragma unroll
    for (int j = 0; j < 3; ++j) {
      const int r = wc * 48 + j * 16 + lr;
      bf[j] = *(const bf16x8*)(rb + 16384 + (r * 8 + (kq ^ (r & 7))) * 16);
    }
    __builtin_amdgcn_s_setprio(1);
#pragma unroll
    for (int i = 0; i < 4; ++i)
#pragma unroll
      for (int j = 0; j < 3; ++j)
        acc[i][j] = __builtin_amdgcn_mfma_f32_16x16x32_bf16(bf[j], af[i],
                                                            acc[i][j], 0, 0, 0);
    __builtin_amdgcn_s_setprio(0);
    // ---- k-half 1
#pragma unroll
    for (int i = 0; i < 4; ++i) {
      const int r = wr * 64 + i * 16 + lr;
      af[i] = *(const bf16x8*)(rb + (r * 8 + ((4 + kq) ^ (r & 7))) * 16);
    }
#pragma unroll
    for (int j = 0; j < 3; ++j) {
      const int r = wc * 48 + j * 16 + lr;
      bf[j] = *(const bf16x8*)(rb + 16384 + (r * 8 + ((4 + kq) ^ (r & 7))) * 16);
    }
    __builtin_amdgcn_s_setprio(1);
#pragma unroll
    for (int i = 0; i < 4; ++i)
#pragma unroll
      for (int j = 0; j < 3; ++j)
        acc[i][j] = __builtin_amdgcn_mfma_f32_16x16x32_bf16(bf[j], af[i],
                                                            acc[i][j], 0, 0, 0);
    __builtin_amdgcn_s_setprio(0);
    if (++cur == 3) cur = 0;
  }

  {  // ---- last K-tile, peeled: full drain, no staging
    const char* rb = smem + cur * 40960;
    bf16x8 af[4], bf[3];
    PIPE_SYNC(0);
#pragma unroll
    for (int kh = 0; kh < 2; ++kh) {
      const int c0 = kh * 4 + kq;
#pragma unroll
      for (int i = 0; i < 4; ++i) {
        const int r = wr * 64 + i * 16 + lr;
        af[i] = *(const bf16x8*)(rb + (r * 8 + (c0 ^ (r & 7))) * 16);
      }
#pragma unroll
      for (int j = 0; j < 3; ++j) {
        const int r = wc * 48 + j * 16 + lr;
        bf[j] = *(const bf16x8*)(rb + 16384 + (r * 8 + (c0 ^ (r & 7))) * 16);
      }
      __builtin_amdgcn_s_setprio(1);
#pragma unroll
      for (int i = 0; i < 4; ++i)
#pragma unroll
        for (int j = 0; j < 3; ++j)
          acc[i][j] = __builtin_amdgcn_mfma_f32_16x16x32_bf16(bf[j], af[i],
                                                              acc[i][j], 0, 0, 0);
      __builtin_amdgcn_s_setprio(0);
    }
  }

  // epilogue: out[b][chan][tok] = resid + acc + bias, 3 x 64-chan slices
  {
    float* tile = (float*)smem;
    const int b = m0 >> 10, tok0 = m0 & (N_ - 1);
#pragma unroll
    for (int sl = 0; sl < 3; ++sl) {
      __syncthreads();
#pragma unroll
      for (int j = 0; j < 3; ++j) {
        const int nl0 = wc * 48 + j * 16 + kq * 4;
        if (((wc * 48 + j * 16) >> 6) == sl) {   // wave-uniform
          const int n = n0 + nl0;
          const f32x4 bv = *(const f32x4*)(bias + n);
#pragma unroll
          for (int i = 0; i < 4; ++i) {
            const int ml = wr * 64 + i * 16 + lr;
            const float* rp = resid + (size_t)(m0 + ml) * C_ + n;
            f32x4 old = *(const f32x4*)rp;
            const f32x4 v = acc[i][j];
#pragma unroll
            for (int r = 0; r < 4; ++r)
              tile[(nl0 - sl * 64 + r) * 132 + ml] = old[r] + v[r] + bv[r];
          }
        }
      }
      __syncthreads();
      const int nl = tid & 63, mc = tid >> 6;   // 64 chans x 8 m-chunks of 16
      float* dst = outp + ((size_t)(b * C_ + n0 + sl * 64 + nl)) * N_ +
                   tok0 + mc * 16;
      const float* src = tile + nl * 132 + mc * 16;
#pragma unroll
      for (int q = 0; q < 4; ++q)
        *(f32x4*)(dst + q * 4) = *(const f32x4*)(src + q * 4);
    }
  }
}

// ---------------------------------------------------------------------------
// Flash attention: 1-D grid 768 blocks, 256 thr, 3 blocks/CU.
// XCD REMAP: g = bid&7 owns heads [12g, 12g+12) x all 8 q-tiles.
// ---------------------------------------------------------------------------
__global__ __launch_bounds__(256, 3) void flash_attn(
    const bf16* __restrict__ Qb, const bf16* __restrict__ Kb,
    const bf16* __restrict__ Vt, bf16* __restrict__ attn) {
  __shared__ __align__(16) bf16 ksm[2][64 * 64];
  __shared__ __align__(16) bf16 vsm[2][64 * 64];
  __shared__ __align__(16) bf16 psm[4][32 * 64];

  const int tid = threadIdx.x, wave = tid >> 6, lane = tid & 63;
  const int lr = lane & 15, kq = lane >> 4;
  const int bid = blockIdx.x;
  const int g = bid & 7, s = bid >> 3;          // s in [0,96)
  const int head = g * 12 + (s % 12);           // XCD g owns 12 heads
  const int qt = s / 12;                        // q-tile 0..7
  const int b = head / NH_, hh = head - b * NH_;
  const int q0 = qt * 128;
  const bf16* Qh = Qb + (size_t)head * (N_ * HD_);
  const bf16* Kh = Kb + (size_t)head * (N_ * HD_);
  const bf16* Vh = Vt + (size_t)head * (HD_ * N_);
  char* pw = (char*)&psm[wave][0];

  bf16x8 qf[2][2];
#pragma unroll
  for (int j = 0; j < 2; ++j)
#pragma unroll
    for (int kh = 0; kh < 2; ++kh)
      qf[j][kh] = *(const bf16x8*)(Qh +
                                   (size_t)(q0 + wave * 32 + j * 16 + lr) * HD_ +
                                   kh * 32 + kq * 8);

  f32x4 o[4][2];
#pragma unroll
  for (int i = 0; i < 4; i++)
#pragma unroll
    for (int j = 0; j < 2; j++) o[i][j] = (f32x4){0.f, 0.f, 0.f, 0.f};
  float mprev[2] = {-1e30f, -1e30f}, lacc[2] = {0.f, 0.f};

  auto stage = [&](int t, int bi) {
#pragma unroll
    for (int it = 0; it < 2; ++it) {
      int s2 = it * 256 + tid;
      int r = s2 >> 3, seg = (s2 & 7) ^ (r & 7);
      gload_lds16(Kh + (size_t)(t * 64 + r) * HD_ + seg * 8,
                  (char*)ksm[bi] + (it * 256 + wave * 64) * 16);
    }
#pragma unroll
    for (int it = 0; it < 2; ++it) {
      int s2 = it * 256 + tid;
      int r = s2 >> 3, seg = (s2 & 7) ^ (r & 7);
      gload_lds16(Vh + (size_t)r * N_ + t * 64 + seg * 8,
                  (char*)vsm[bi] + (it * 256 + wave * 64) * 16);
    }
  };

  stage(0, 0);

  for (int t = 0; t < 16; ++t) {
    const int bi = t & 1;
    __syncthreads();
    if (t < 15) stage(t + 1, bi ^ 1);

    f32x4 sacc[4][2];
#pragma unroll
    for (int i = 0; i < 4; ++i) {
#pragma unroll
      for (int j = 0; j < 2; ++j) sacc[i][j] = (f32x4){0.f, 0.f, 0.f, 0.f};
      int row = i * 16 + lr;
      bf16x8 kf0 = *(const bf16x8*)((char*)ksm[bi] + row * 128 +
                                    ((kq ^ (row & 7)) * 16));
      bf16x8 kf1 = *(const bf16x8*)((char*)ksm[bi] + row * 128 +
                                    (((4 + kq) ^ (row & 7)) * 16));
#pragma unroll
      for (int j = 0; j < 2; ++j) {
        sacc[i][j] = __builtin_amdgcn_mfma_f32_16x16x32_bf16(kf0, qf[j][0],
                                                             sacc[i][j], 0, 0, 0);
        sacc[i][j] = __builtin_amdgcn_mfma_f32_16x16x32_bf16(kf1, qf[j][1],
                                                             sacc[i][j], 0, 0, 0);
      }
    }

#pragma unroll
    for (int j = 0; j < 2; ++j) {
      float mx = -1e30f;
#pragma unroll
      for (int i = 0; i < 4; ++i)
#pragma unroll
        for (int r = 0; r < 4; ++r) mx = fmaxf(mx, sacc[i][j][r]);
      mx = fmaxf(mx, __shfl_xor(mx, 16));
      mx = fmaxf(mx, __shfl_xor(mx, 32));
      float mnew = fmaxf(mprev[j], mx);
      float alpha = __builtin_amdgcn_exp2f((mprev[j] - mnew) * FA_C);
      mprev[j] = mnew;
      float rs = 0.f;
      const int prow = j * 16 + lr;
#pragma unroll
      for (int i = 0; i < 4; ++i) {
        float p0 = __builtin_amdgcn_exp2f((sacc[i][j][0] - mnew) * FA_C);
        float p1 = __builtin_amdgcn_exp2f((sacc[i][j][1] - mnew) * FA_C);
        float p2 = __builtin_amdgcn_exp2f((sacc[i][j][2] - mnew) * FA_C);
        float p3 = __builtin_amdgcn_exp2f((sacc[i][j][3] - mnew) * FA_C);
        rs += (p0 + p1) + (p2 + p3);
        bf16x4 pk = {(bf16)p0, (bf16)p1, (bf16)p2, (bf16)p3};
        int c = i * 2 + (kq >> 1);
        *(bf16x4*)(pw + prow * 128 + ((c ^ (prow & 7)) * 16) + (kq & 1) * 8) = pk;
      }
      rs += __shfl_xor(rs, 16);
      rs += __shfl_xor(rs, 32);
      lacc[j] = lacc[j] * alpha + rs;
#pragma unroll
      for (int i = 0; i < 4; ++i) {
        o[i][j][0] *= alpha; o[i][j][1] *= alpha;
        o[i][j][2] *= alpha; o[i][j][3] *= alpha;
      }
    }

#pragma unroll
    for (int k0c = 0; k0c < 2; ++k0c) {
      bf16x8 pf[2];
#pragma unroll
      for (int j = 0; j < 2; ++j) {
        int prow = j * 16 + lr, c = k0c * 4 + kq;
        pf[j] = *(const bf16x8*)(pw + prow * 128 + ((c ^ (prow & 7)) * 16));
      }
#pragma unroll
      for (int i = 0; i < 4; ++i) {
        int d = i * 16 + lr, c = k0c * 4 + kq;
        bf16x8 vf = *(const bf16x8*)((char*)vsm[bi] + d * 128 +
                                     ((c ^ (d & 7)) * 16));
#pragma unroll
        for (int j = 0; j < 2; ++j)
          o[i][j] = __builtin_amdgcn_mfma_f32_16x16x32_bf16(vf, pf[j], o[i][j],
                                                            0, 0, 0);
      }
    }
  }

#pragma unroll
  for (int j = 0; j < 2; ++j) {
    float inv = 1.0f / lacc[j];
    int tok = q0 + wave * 32 + j * 16 + lr;
    bf16* op = attn + ((size_t)(b * N_ + tok)) * C_ + hh * HD_;
#pragma unroll
    for (int i = 0; i < 4; ++i) {
      bf16x4 pk = {(bf16)(o[i][j][0] * inv), (bf16)(o[i][j][1] * inv),
                   (bf16)(o[i][j][2] * inv), (bf16)(o[i][j][3] * inv)};
      *(bf16x4*)(op + i * 16 + kq * 4) = pk;
    }
  }
}

// ---------------------------------------------------------------------------
__global__ __launch_bounds__(256) void cast_all(
    const float* __restrict__ a, int na, const float* __restrict__ b, int nb,
    const float* __restrict__ c, int nc, const float* __restrict__ d,
    bf16* __restrict__ dst) {
  int i = (blockIdx.x * 256 + threadIdx.x) * 4;
  const float* src;
  int off;
  if (i < na) { src = a; off = i; }
  else if (i < na + nb) { src = b; off = i - na; }
  else if (i < na + nb + nc) { src = c; off = i - na - nb; }
  else { src = d; off = i - na - nb - nc; }
  float4 v = *(const float4*)(src + off);
  bf16x4 o = {(bf16)v.x, (bf16)v.y, (bf16)v.z, (bf16)v.w};
  *(bf16x4*)(dst + i) = o;
}

// depthwise 3x3 conv + bias + residual, fused transpose NCHW -> [B,N,C]
__global__ __launch_bounds__(256) void conv_pe_t(const float* __restrict__ x,
                                                 const float* __restrict__ cw,
                                                 const float* __restrict__ cb,
                                                 float* __restrict__ t0) {
  __shared__ float tile[32][33];
  const int h = blockIdx.x, ct = blockIdx.y, b = blockIdx.z;
  const int tid = threadIdx.x;
  const int w = tid & 31, cs = tid >> 5;
#pragma unroll
  for (int cc = cs; cc < 32; cc += 8) {
    int c = ct * 32 + cc;
    const float* xp = x + ((size_t)(b * C_ + c)) * 1024;
    const float* wp = cw + c * 9;
    float s = cb[c] + xp[h * 32 + w];
#pragma unroll
    for (int ky = 0; ky < 3; ++ky) {
      int hy = h + ky - 1;
      if ((unsigned)hy < 32u) {
#pragma unroll
        for (int kx = 0; kx < 3; ++kx) {
          int wx = w + kx - 1;
          if ((unsigned)wx < 32u) s += xp[hy * 32 + wx] * wp[ky * 3 + kx];
        }
      }
    }
    tile[cc][w] = s;
  }
  __syncthreads();
  const int cc = tid & 31;
#pragma unroll
  for (int wc = tid >> 5; wc < 32; wc += 8)
    t0[((size_t)(b * N_) + h * 32 + wc) * C_ + ct * 32 + cc] = tile[cc][wc];
}

// LayerNorm over C=768, fp32 in, bf16 out
__global__ __launch_bounds__(256) void ln_bf16(const float* __restrict__ t,
                                               const float* __restrict__ g,
                                               const float* __restrict__ be,
                                               bf16* __restrict__ out) {
  int row = blockIdx.x, tid = threadIdx.x;
  const float* p = t + (size_t)row * C_;
  float v0 = p[tid], v1 = p[tid + 256], v2 = p[tid + 512];
  __shared__ float rs[256], rq[256];
  rs[tid] = v0 + v1 + v2;
  rq[tid] = v0 * v0 + v1 * v1 + v2 * v2;
  __syncthreads();
  for (int off = 128; off; off >>= 1) {
    if (tid < off) {
      rs[tid] += rs[tid + off];
      rq[tid] += rq[tid + off];
    }
    __syncthreads();
  }
  float mu = rs[0] * (1.f / C_);
  float var = rq[0] * (1.f / C_) - mu * mu;
  float rstd = rsqrtf(var + 1e-5f);
  bf16* q = out + (size_t)row * C_;
  q[tid] = (bf16)((v0 - mu) * rstd * g[tid] + be[tid]);
  q[tid + 256] = (bf16)((v1 - mu) * rstd * g[tid + 256] + be[tid + 256]);
  q[tid + 512] = (bf16)((v2 - mu) * rstd * g[tid + 512] + be[tid + 512]);
}

// ---------------------------------------------------------------------------
extern "C" void kernel_launch(void* const* d_in, const int* in_sizes, int n_in,
                              void* d_out, int out_size, void* d_ws,
                              size_t ws_size, hipStream_t stream) {
  (void)in_sizes; (void)n_in; (void)out_size; (void)ws_size;
  const float* x      = (const float*)d_in[0];
  const float* conv_w = (const float*)d_in[1];
  const float* conv_b = (const float*)d_in[2];
  const float* ln1_g  = (const float*)d_in[3];
  const float* ln1_b  = (const float*)d_in[4];
  const float* qkv_w  = (const float*)d_in[5];
  const float* proj_w = (const float*)d_in[6];
  const float* proj_b = (const float*)d_in[7];
  const float* ln2_g  = (const float*)d_in[8];
  const float* ln2_b  = (const float*)d_in[9];
  const float* fc1_w  = (const float*)d_in[10];
  const float* fc1_b  = (const float*)d_in[11];
  const float* fc2_w  = (const float*)d_in[12];
  const float* fc2_b  = (const float*)d_in[13];
  float* out = (float*)d_out;

  char* w = (char*)d_ws;
  auto carve = [&](size_t bytes) {
    char* p = w;
    w += (bytes + 255) & ~(size_t)255;
    return p;
  };
  bf16* hid   = (bf16*)carve((size_t)NTOK * HID_ * 2);
  float* t0   = (float*)carve((size_t)NTOK * C_ * 4);
  bf16* lnout = (bf16*)carve((size_t)NTOK * C_ * 2);
  bf16* wq    = (bf16*)carve((size_t)3 * C_ * C_ * 2);
  bf16* wp    = (bf16*)carve((size_t)C_ * C_ * 2);
  bf16* w1    = (bf16*)carve((size_t)HID_ * C_ * 2);
  bf16* w2    = (bf16*)carve((size_t)C_ * HID_ * 2);
  bf16* Qb    = (bf16*)carve((size_t)NHEADS * N_ * HD_ * 2);
  bf16* Kb    = (bf16*)carve((size_t)NHEADS * N_ * HD_ * 2);
  bf16* Vt    = (bf16*)carve((size_t)NHEADS * HD_ * N_ * 2);
  bf16* attn  = (bf16*)carve((size_t)NTOK * C_ * 2);

  const int na = 3 * C_ * C_, nb = C_ * C_, nc = HID_ * C_, nd = C_ * HID_;
  cast_all<<<(na + nb + nc + nd) / 1024, 256, 0, stream>>>(
      qkv_w, na, proj_w, nb, fc1_w, nc, fc2_w, wq);

  conv_pe_t<<<dim3(32, C_ / 32, B_), 256, 0, stream>>>(x, conv_w, conv_b, t0);

  // QKV: gemm_pipe 128x192 tribuf, 64m x 12n = 768 blocks = 3 exact rounds
  ln_bf16<<<NTOK, 256, 0, stream>>>(t0, ln1_g, ln1_b, lnout);
  gemm_pipe<0><<<768, 512, 0, stream>>>(lnout, wq, 768, 768, 768, 12,
                                        Qb, Kb, Vt, nullptr, nullptr);

  // flash: 1-D grid, head-per-XCD remap (12 heads x 8 q-tiles per XCD)
  flash_attn<<<768, 256, 0, stream>>>(Qb, Kb, Vt, attn);

  // proj: gemm_pipe 128x192 tribuf, 64m x 4n = 256 blocks = 1 exact round
  gemm_pipe<1><<<256, 512, 0, stream>>>(attn, wp, 768, 768, 768, 4,
                                        nullptr, nullptr, nullptr, t0, proj_b);
  ln_bf16<<<NTOK, 256, 0, stream>>>(t0, ln2_g, ln2_b, lnout);
  // fc1: R9-best 256x192 4-phase (512 blocks = 2 exact rounds)
  gemm_fc1<<<512, 512, 0, stream>>>(lnout, w1, fc1_b, hid, 768, 768, 768,
                                    16, 4, HID_);
  // fc2: R10-best 128x192 tribuf (256 blocks = 1 round), NCHW epilogue
  gemm_fc2<<<256, 512, 0, stream>>>(hid, w2, fc2_b, t0, out, 3072, 3072, 3072);
}